// Round 4
// baseline (70.243 us; speedup 1.0000x reference)
//
#include <hip/hip_runtime.h>
#include <math.h>

#define NPAIR 630
#define EPS_F 1.1920928955078125e-07f   // np.finfo(float32).eps
#define FXSCALE 16777216.0              // 2^24 fixed-point scale

// decode pair index m in [0,630) -> (i,j), i<j<36, row-major triu order
__device__ __forceinline__ void decode_pair(int m, int& pi, int& pj) {
    int i = (int)((71.0f - sqrtf(5041.0f - 8.0f * (float)m)) * 0.5f);
    i = max(0, min(34, i));
    while (i > 0 && m < i * (71 - i) / 2) --i;
    while (i < 34 && m >= (i + 1) * (70 - i) / 2) ++i;
    pi = i;
    pj = m - i * (71 - i) / 2 + i + 1;
}

// pts[i] for i in [0,36): lanes 0-17 hold base coords; i>=18 is exact negation
__device__ __forceinline__ float fetch_pt(float v, int i) {
    int ii = (i < 18) ? i : (i - 18);
    float r = __shfl(v, ii, 64);
    return (i < 18) ? r : -r;
}

__device__ __forceinline__ float shoe4(float X0,float Y0,float X1,float Y1,
                                       float X2,float Y2,float X3,float Y3) {
    float s = 0.f;
    s += X0 * Y1 - Y0 * X1;
    s += X1 * Y2 - Y1 * X2;
    s += X2 * Y3 - Y2 * X3;
    s += X3 * Y0 - Y3 * X0;
    return 0.5f * fabsf(s);
}

// scan pairs m = lane + 64*sub + 128*it (it<5) for one poly; packed (area,m) min
__device__ __forceinline__ unsigned long long pair_scan(
    const float* PX, const float* PY, float xv, float yv, int lane, int sub)
{
    unsigned long long best = ~0ULL;
#pragma unroll
    for (int it = 0; it < 5; ++it) {
        int m = lane + (sub << 6) + (it << 7);
        if (m < NPAIR) {
            int i, j; decode_pair(m, i, j);
            float xi = fetch_pt(xv, i), yi = fetch_pt(yv, i);
            float xj = fetch_pt(xv, j), yj = fetch_pt(yv, j);
            float dx = xj - xi, dy = yj - yi;
            float nrm = sqrtf(dx * dx + dy * dy);
            float inv = 1.f / fmaxf(nrm, 1e-9f);
            float ux = dx * inv, uy = dy * inv;
            float vx = -uy, vy = ux;
            float umax = 0.f, vmax = 0.f;   // max |proj|; == fmax(pmax,-pmin) exactly
#pragma unroll
            for (int kk = 0; kk < 18; ++kk) {
                float x = PX[kk], y = PY[kk];
                float pu = ux * x + uy * y;
                float pv = vx * x + vy * y;
                umax = fmaxf(umax, fabsf(pu));
                vmax = fmaxf(vmax, fabsf(pv));
            }
            float area = (umax + umax) * (vmax + vmax);
            area = (nrm > 1e-9f) ? area : INFINITY;
            unsigned long long key =
                ((unsigned long long)__float_as_uint(area) << 32) | (unsigned)m;
            if (key < best) best = key;
        }
    }
#pragma unroll
    for (int off = 1; off < 64; off <<= 1) {
        unsigned long long o = __shfl_xor(best, off, 64);
        if (o < best) best = o;
    }
    return best;
}

// finalize rect from winning pair key; all lanes return sorted corners
__device__ __forceinline__ void rect_finalize(
    const float* PX, const float* PY, float xv, float yv,
    unsigned long long key,
    float& c0x, float& c0y, float& c1x, float& c1y,
    float& c2x, float& c2y, float& c3x, float& c3y)
{
    int m = (int)(key & 0xFFFFFFFFULL);
    int i, j; decode_pair(m, i, j);
    float xi = fetch_pt(xv, i), yi = fetch_pt(yv, i);
    float xj = fetch_pt(xv, j), yj = fetch_pt(yv, j);
    float dx = xj - xi, dy = yj - yi;
    float nrm = sqrtf(dx * dx + dy * dy);
    float inv = 1.f / fmaxf(nrm, 1e-9f);
    float ux = dx * inv, uy = dy * inv;
    float vx = -uy, vy = ux;
    float umax = 0.f, vmax = 0.f;
#pragma unroll
    for (int kk = 0; kk < 18; ++kk) {
        float x = PX[kk], y = PY[kk];
        float pu = ux * x + uy * y;
        float pv = vx * x + vy * y;
        umax = fmaxf(umax, fabsf(pu));
        vmax = fmaxf(vmax, fabsf(pv));
    }
    float umin = -umax, vmin = -vmax;
    float cu0 = umin, cu1 = umax, cu2 = umax, cu3 = umin;
    float cv0 = vmin, cv1 = vmin, cv2 = vmax, cv3 = vmax;
    float x0 = cu0 * ux + cv0 * vx, y0 = cu0 * uy + cv0 * vy;
    float x1 = cu1 * ux + cv1 * vx, y1 = cu1 * uy + cv1 * vy;
    float x2 = cu2 * ux + cv2 * vx, y2 = cu2 * uy + cv2 * vy;
    float x3 = cu3 * ux + cv3 * vx, y3 = cu3 * uy + cv3 * vy;
    float a0 = atan2f(y0, x0), a1 = atan2f(y1, x1);
    float a2 = atan2f(y2, x2), a3 = atan2f(y3, x3);
    int q0 = 0, q1 = 1, q2 = 2, q3 = 3;
#define CSWP(aA,qA,xA,yA, aB,qB,xB,yB) \
    { bool sw = (aA > aB) || (aA == aB && qA > qB); \
      if (sw) { float tf; int ti; \
        tf = aA; aA = aB; aB = tf;  ti = qA; qA = qB; qB = ti; \
        tf = xA; xA = xB; xB = tf;  tf = yA; yA = yB; yB = tf; } }
    CSWP(a0,q0,x0,y0, a1,q1,x1,y1)
    CSWP(a2,q2,x2,y2, a3,q3,x3,y3)
    CSWP(a0,q0,x0,y0, a2,q2,x2,y2)
    CSWP(a1,q1,x1,y1, a3,q3,x3,y3)
    CSWP(a1,q1,x1,y1, a2,q2,x2,y2)
#undef CSWP
    c0x = x0; c0y = y0; c1x = x1; c1y = y1;
    c2x = x2; c2y = y2; c3x = x3; c3y = y3;
}

// one Sutherland-Hodgman step, literal lane-parallel copy of _clip_halfplane
template <int K>
__device__ __forceinline__ void clip_step(float& x, float& y,
    float e1x, float e1y, float e2x, float e2y, int lane)
{
    const float dex = e2x - e1x, dey = e2y - e1y;
    float side = dex * (y - e1y) - dey * (x - e1x);
    int nl = (lane + 1) % K;
    float xn = __shfl(x, nl, 64);
    float yn = __shfl(y, nl, 64);
    float siden = __shfl(side, nl, 64);
    float denom = side - siden;
    float dd = (fabsf(denom) < 1e-12f) ? 1e-12f : denom;
    float t = side / dd;
    float ix = x + t * (xn - x);
    float iy = y + t * (yn - y);
    bool s_in = side >= 0.f, e_in = siden >= 0.f;
    int flags = (s_in ? 1 : 0) | (e_in ? 2 : 0);
    int src = lane >> 1;
    float ex  = __shfl(ix, src, 64);
    float ey  = __shfl(iy, src, 64);
    float nx2 = __shfl(xn, src, 64);
    float ny2 = __shfl(yn, src, 64);
    int   f2  = __shfl(flags, src, 64);
    bool odd = (lane & 1) != 0;
    float ox = odd ? nx2 : ex;
    float oy = odd ? ny2 : ey;
    bool sin2 = (f2 & 1) != 0, ein2 = (f2 & 2) != 0;
    bool vj = odd ? ein2 : (sin2 != ein2);
    vj = vj && (lane < 2 * K);
    int idx = vj ? lane : -1;
#pragma unroll
    for (int off = 1; off < 64; off <<= 1) {
        int o = __shfl_up(idx, off, 64);
        if (lane >= off && o > idx) idx = o;
    }
    unsigned long long bal = __ballot(vj);
    int firstv = (int)__ffsll(bal) - 1;
    int gi = (idx >= 0) ? idx : firstv;
    float gx = __shfl(ox, gi, 64);
    float gy = __shfl(oy, gi, 64);
    if (bal == 0ULL) { gx = 0.f; gy = 0.f; }
    x = gx; y = gy;
}

__global__ __launch_bounds__(256) void iou_fused_kernel(
    const float* __restrict__ output, const int* __restrict__ mask,
    const int* __restrict__ ind, const float* __restrict__ target,
    unsigned long long* __restrict__ acc, float* __restrict__ out)
{
    const int row  = blockIdx.x;      // 0 .. 1023
    const int b    = row >> 6;
    const int tid  = threadIdx.x;
    const int lane = tid & 63;
    const int wid  = tid >> 6;        // 0..3
    const int poly = wid >> 1;        // waves 0,1 -> pred; 2,3 -> target
    const int sub  = wid & 1;

    __shared__ unsigned long long wkey[4];
    __shared__ float cXs[4], cYs[4];  // poly-1 sorted corners

    const int idx = ind[row];
    float p = 0.f, t = 0.f, termv = 0.f, cosv = 0.f, sinv = 0.f;
    if (lane < 18) {
        float ang = (float)lane * ((float)M_PI / 18.0f);
        cosv = cosf(ang); sinv = sinf(ang);
        if (poly == 0) p = output[(size_t)(b * 18 + lane) * 65536 + idx];
        if (poly == 1 || wid == 0) t = target[row * 18 + lane];
        if (wid == 0) {
            float d = p - t, ad = fabsf(d);
            termv = (ad < 1.f) ? 0.5f * d * d : (ad - 0.5f);
        }
    }
    float base = (poly == 0) ? p : t;
    float xv = base * cosv, yv = base * sinv;

    float PX[18], PY[18];
#pragma unroll
    for (int k = 0; k < 18; ++k) {
        PX[k] = __shfl(xv, k, 64);
        PY[k] = __shfl(yv, k, 64);
    }

    unsigned long long best = pair_scan(PX, PY, xv, yv, lane, sub);
    if (lane == 0) wkey[wid] = best;

    // wave 0: smooth-L1 mean in sequential order (matches np)
    float sl1 = 0.f;
    if (wid == 0) {
#pragma unroll
        for (int k = 0; k < 18; ++k) sl1 += __shfl(termv, k, 64);
        sl1 = sl1 / 18.0f;
    }
    __syncthreads();

    float ax0,ay0,ax1,ay1,ax2,ay2,ax3,ay3;
    if (sub == 0) {   // wave 0 finalizes poly 0, wave 2 finalizes poly 1
        unsigned long long k0 = wkey[2 * poly], k1 = wkey[2 * poly + 1];
        unsigned long long kk = (k1 < k0) ? k1 : k0;
        rect_finalize(PX, PY, xv, yv, kk, ax0,ay0,ax1,ay1,ax2,ay2,ax3,ay3);
        if (wid == 2 && lane == 0) {
            cXs[0] = ax0; cYs[0] = ay0; cXs[1] = ax1; cYs[1] = ay1;
            cXs[2] = ax2; cYs[2] = ay2; cXs[3] = ax3; cYs[3] = ay3;
        }
    }
    __syncthreads();

    if (wid == 0) {
        float bx0 = cXs[0], by0 = cYs[0], bx1 = cXs[1], by1 = cYs[1];
        float bx2 = cXs[2], by2 = cYs[2], bx3 = cXs[3], by3 = cYs[3];

        float areaA = shoe4(ax0,ay0,ax1,ay1,ax2,ay2,ax3,ay3);
        float areaB = shoe4(bx0,by0,bx1,by1,bx2,by2,bx3,by3);

        int s3 = lane & 3;
        float px = (s3 == 0) ? ax0 : (s3 == 1) ? ax1 : (s3 == 2) ? ax2 : ax3;
        float py = (s3 == 0) ? ay0 : (s3 == 1) ? ay1 : (s3 == 2) ? ay2 : ay3;
        clip_step<4 >(px, py, bx0, by0, bx1, by1, lane);
        clip_step<8 >(px, py, bx1, by1, bx2, by2, lane);
        clip_step<16>(px, py, bx2, by2, bx3, by3, lane);
        clip_step<32>(px, py, bx3, by3, bx0, by0, lane);

        float xn = __shfl(px, (lane + 1) & 63, 64);
        float yn = __shfl(py, (lane + 1) & 63, 64);
        float term = px * yn - py * xn;
#pragma unroll
        for (int off = 1; off < 64; off <<= 1) term += __shfl_xor(term, off, 64);
        float inter = 0.5f * fabsf(term);

        float uni = areaA + areaB - inter;
        float iou = inter / fmaxf(uni, 1e-12f);

        if (lane == 0) {
            int mk = mask[row];
            float mf = (float)mk;
            float alpha = -logf(fabsf(iou) + EPS_F);
            float li = alpha * sl1 / (fabsf(sl1) + EPS_F);
            long long v1 = __double2ll_rn((double)(sl1 * mf) * FXSCALE);
            long long v2 = __double2ll_rn((double)(li  * mf) * FXSCALE);
            atomicAdd(&acc[0], (unsigned long long)v1);
            atomicAdd(&acc[1], (unsigned long long)v2);
            atomicAdd(&acc[2], (unsigned long long)(long long)mk);
            __threadfence();
            unsigned long long old = atomicAdd(&acc[3], 1ULL);
            if (old == (unsigned long long)(gridDim.x - 1)) {
                long long s1 = (long long)atomicAdd(&acc[0], 0ULL);
                long long s2 = (long long)atomicAdd(&acc[1], 0ULL);
                long long sc = (long long)atomicAdd(&acc[2], 0ULL);
                double cnt = fmax((double)sc, 1.0);
                out[0] = (float)(((double)s1 / FXSCALE) / cnt);
                out[1] = (float)(((double)s2 / FXSCALE) / cnt);
            }
        }
    }
}

extern "C" void kernel_launch(void* const* d_in, const int* in_sizes, int n_in,
                              void* d_out, int out_size, void* d_ws, size_t ws_size,
                              hipStream_t stream) {
    const float* output = (const float*)d_in[0];
    const int*   mask   = (const int*)d_in[1];
    const int*   ind    = (const int*)d_in[2];
    const float* target = (const float*)d_in[3];
    float* out = (float*)d_out;
    unsigned long long* acc = (unsigned long long*)d_ws;

    hipMemsetAsync(d_ws, 0, 4 * sizeof(unsigned long long), stream);
    iou_fused_kernel<<<1024, 256, 0, stream>>>(output, mask, ind, target, acc, out);
}

// Round 5
// 22.019 us; speedup vs baseline: 3.1901x; 3.1901x over previous
//
#include <hip/hip_runtime.h>
#include <math.h>

#define NPAIR 630
#define EPS_F 1.1920928955078125e-07f   // np.finfo(float32).eps

// decode pair index m in [0,630) -> (i,j), i<j<36, row-major triu order
__device__ __forceinline__ void decode_pair(int m, int& pi, int& pj) {
    int i = (int)((71.0f - sqrtf(5041.0f - 8.0f * (float)m)) * 0.5f);
    i = max(0, min(34, i));
    while (i > 0 && m < i * (71 - i) / 2) --i;
    while (i < 34 && m >= (i + 1) * (70 - i) / 2) ++i;
    pi = i;
    pj = m - i * (71 - i) / 2 + i + 1;
}

// pts[i] for i in [0,36): lanes 0-17 hold base coords; i>=18 is exact negation
__device__ __forceinline__ float fetch_pt(float v, int i) {
    int ii = (i < 18) ? i : (i - 18);
    float r = __shfl(v, ii, 64);
    return (i < 18) ? r : -r;
}

__device__ __forceinline__ float shoe4(float X0,float Y0,float X1,float Y1,
                                       float X2,float Y2,float X3,float Y3) {
    float s = 0.f;
    s += X0 * Y1 - Y0 * X1;
    s += X1 * Y2 - Y1 * X2;
    s += X2 * Y3 - Y2 * X3;
    s += X3 * Y0 - Y3 * X0;
    return 0.5f * fabsf(s);
}

// scan pairs m = lane + 64*sub + 128*it (it<5) for one poly; packed (area,m) min
__device__ __forceinline__ unsigned long long pair_scan(
    const float* PX, const float* PY, float xv, float yv, int lane, int sub)
{
    unsigned long long best = ~0ULL;
#pragma unroll
    for (int it = 0; it < 5; ++it) {
        int m = lane + (sub << 6) + (it << 7);
        if (m < NPAIR) {
            int i, j; decode_pair(m, i, j);
            float xi = fetch_pt(xv, i), yi = fetch_pt(yv, i);
            float xj = fetch_pt(xv, j), yj = fetch_pt(yv, j);
            float dx = xj - xi, dy = yj - yi;
            float nrm = sqrtf(dx * dx + dy * dy);
            float inv = 1.f / fmaxf(nrm, 1e-9f);
            float ux = dx * inv, uy = dy * inv;
            float vx = -uy, vy = ux;
            float umax = 0.f, vmax = 0.f;   // max |proj| == fmax(pmax,-pmin) exactly
#pragma unroll
            for (int kk = 0; kk < 18; ++kk) {
                float x = PX[kk], y = PY[kk];
                float pu = ux * x + uy * y;
                float pv = vx * x + vy * y;
                umax = fmaxf(umax, fabsf(pu));
                vmax = fmaxf(vmax, fabsf(pv));
            }
            float area = (umax + umax) * (vmax + vmax);
            area = (nrm > 1e-9f) ? area : INFINITY;
            unsigned long long key =
                ((unsigned long long)__float_as_uint(area) << 32) | (unsigned)m;
            if (key < best) best = key;
        }
    }
#pragma unroll
    for (int off = 1; off < 64; off <<= 1) {
        unsigned long long o = __shfl_xor(best, off, 64);
        if (o < best) best = o;
    }
    return best;
}

// finalize rect from winning pair key; corners returned in CCW construction
// order (== reference's angle-sorted cycle up to rotation; shoelace and
// Sutherland-Hodgman are cyclic-rotation-invariant, so no atan2/sort needed)
__device__ __forceinline__ void rect_finalize(
    const float* PX, const float* PY, float xv, float yv,
    unsigned long long key,
    float& c0x, float& c0y, float& c1x, float& c1y,
    float& c2x, float& c2y, float& c3x, float& c3y)
{
    int m = (int)(key & 0xFFFFFFFFULL);
    int i, j; decode_pair(m, i, j);
    float xi = fetch_pt(xv, i), yi = fetch_pt(yv, i);
    float xj = fetch_pt(xv, j), yj = fetch_pt(yv, j);
    float dx = xj - xi, dy = yj - yi;
    float nrm = sqrtf(dx * dx + dy * dy);
    float inv = 1.f / fmaxf(nrm, 1e-9f);
    float ux = dx * inv, uy = dy * inv;
    float vx = -uy, vy = ux;
    float umax = 0.f, vmax = 0.f;
#pragma unroll
    for (int kk = 0; kk < 18; ++kk) {
        float x = PX[kk], y = PY[kk];
        float pu = ux * x + uy * y;
        float pv = vx * x + vy * y;
        umax = fmaxf(umax, fabsf(pu));
        vmax = fmaxf(vmax, fabsf(pv));
    }
    float umin = -umax, vmin = -vmax;
    // CCW cycle: (umin,vmin) (umax,vmin) (umax,vmax) (umin,vmax)
    c0x = umin * ux + vmin * vx;  c0y = umin * uy + vmin * vy;
    c1x = umax * ux + vmin * vx;  c1y = umax * uy + vmin * vy;
    c2x = umax * ux + vmax * vx;  c2y = umax * uy + vmax * vy;
    c3x = umin * ux + vmax * vx;  c3y = umin * uy + vmax * vy;
}

// one Sutherland-Hodgman step, literal lane-parallel copy of _clip_halfplane
template <int K>
__device__ __forceinline__ void clip_step(float& x, float& y,
    float e1x, float e1y, float e2x, float e2y, int lane)
{
    const float dex = e2x - e1x, dey = e2y - e1y;
    float side = dex * (y - e1y) - dey * (x - e1x);
    int nl = (lane + 1) % K;
    float xn = __shfl(x, nl, 64);
    float yn = __shfl(y, nl, 64);
    float siden = __shfl(side, nl, 64);
    float denom = side - siden;
    float dd = (fabsf(denom) < 1e-12f) ? 1e-12f : denom;
    float t = side / dd;
    float ix = x + t * (xn - x);
    float iy = y + t * (yn - y);
    bool s_in = side >= 0.f, e_in = siden >= 0.f;
    int flags = (s_in ? 1 : 0) | (e_in ? 2 : 0);
    int src = lane >> 1;
    float ex  = __shfl(ix, src, 64);
    float ey  = __shfl(iy, src, 64);
    float nx2 = __shfl(xn, src, 64);
    float ny2 = __shfl(yn, src, 64);
    int   f2  = __shfl(flags, src, 64);
    bool odd = (lane & 1) != 0;
    float ox = odd ? nx2 : ex;
    float oy = odd ? ny2 : ey;
    bool sin2 = (f2 & 1) != 0, ein2 = (f2 & 2) != 0;
    bool vj = odd ? ein2 : (sin2 != ein2);
    vj = vj && (lane < 2 * K);
    int idx = vj ? lane : -1;
#pragma unroll
    for (int off = 1; off < 64; off <<= 1) {
        int o = __shfl_up(idx, off, 64);
        if (lane >= off && o > idx) idx = o;
    }
    unsigned long long bal = __ballot(vj);
    int firstv = (int)__ffsll(bal) - 1;
    int gi = (idx >= 0) ? idx : firstv;
    float gx = __shfl(ox, gi, 64);
    float gy = __shfl(oy, gi, 64);
    if (bal == 0ULL) { gx = 0.f; gy = 0.f; }
    x = gx; y = gy;
}

__global__ __launch_bounds__(256) void iou_row_kernel(
    const float* __restrict__ output, const int* __restrict__ mask,
    const int* __restrict__ ind, const float* __restrict__ target,
    float* __restrict__ rowSl1, float* __restrict__ rowLi)
{
    const int row  = blockIdx.x;      // 0 .. 1023
    const int b    = row >> 6;
    const int tid  = threadIdx.x;
    const int lane = tid & 63;
    const int wid  = tid >> 6;        // 0..3
    const int poly = wid >> 1;        // waves 0,1 -> pred; 2,3 -> target
    const int sub  = wid & 1;

    __shared__ unsigned long long wkey[4];
    __shared__ float cXs[4], cYs[4];  // poly-1 sorted corners

    const int idx = ind[row];
    float p = 0.f, t = 0.f, termv = 0.f, cosv = 0.f, sinv = 0.f;
    if (lane < 18) {
        float ang = (float)lane * ((float)M_PI / 18.0f);
        cosv = cosf(ang); sinv = sinf(ang);
        if (poly == 0) p = output[(size_t)(b * 18 + lane) * 65536 + idx];
        if (poly == 1 || wid == 0) t = target[row * 18 + lane];
        if (wid == 0) {
            float d = p - t, ad = fabsf(d);
            termv = (ad < 1.f) ? 0.5f * d * d : (ad - 0.5f);
        }
    }
    float base = (poly == 0) ? p : t;
    float xv = base * cosv, yv = base * sinv;

    float PX[18], PY[18];
#pragma unroll
    for (int k = 0; k < 18; ++k) {
        PX[k] = __shfl(xv, k, 64);
        PY[k] = __shfl(yv, k, 64);
    }

    unsigned long long best = pair_scan(PX, PY, xv, yv, lane, sub);
    if (lane == 0) wkey[wid] = best;

    // wave 0: smooth-L1 mean in sequential order (matches np)
    float sl1 = 0.f;
    if (wid == 0) {
#pragma unroll
        for (int k = 0; k < 18; ++k) sl1 += __shfl(termv, k, 64);
        sl1 = sl1 / 18.0f;
    }
    __syncthreads();

    float ax0,ay0,ax1,ay1,ax2,ay2,ax3,ay3;
    if (sub == 0) {   // wave 0 finalizes poly 0, wave 2 finalizes poly 1
        unsigned long long k0 = wkey[2 * poly], k1 = wkey[2 * poly + 1];
        unsigned long long kk = (k1 < k0) ? k1 : k0;
        rect_finalize(PX, PY, xv, yv, kk, ax0,ay0,ax1,ay1,ax2,ay2,ax3,ay3);
        if (wid == 2 && lane == 0) {
            cXs[0] = ax0; cYs[0] = ay0; cXs[1] = ax1; cYs[1] = ay1;
            cXs[2] = ax2; cYs[2] = ay2; cXs[3] = ax3; cYs[3] = ay3;
        }
    }
    __syncthreads();

    if (wid == 0) {
        float bx0 = cXs[0], by0 = cYs[0], bx1 = cXs[1], by1 = cYs[1];
        float bx2 = cXs[2], by2 = cYs[2], bx3 = cXs[3], by3 = cYs[3];

        float areaA = shoe4(ax0,ay0,ax1,ay1,ax2,ay2,ax3,ay3);
        float areaB = shoe4(bx0,by0,bx1,by1,bx2,by2,bx3,by3);

        int s3 = lane & 3;
        float px = (s3 == 0) ? ax0 : (s3 == 1) ? ax1 : (s3 == 2) ? ax2 : ax3;
        float py = (s3 == 0) ? ay0 : (s3 == 1) ? ay1 : (s3 == 2) ? ay2 : ay3;
        clip_step<4 >(px, py, bx0, by0, bx1, by1, lane);
        clip_step<8 >(px, py, bx1, by1, bx2, by2, lane);
        clip_step<16>(px, py, bx2, by2, bx3, by3, lane);
        clip_step<32>(px, py, bx3, by3, bx0, by0, lane);

        float xn = __shfl(px, (lane + 1) & 63, 64);
        float yn = __shfl(py, (lane + 1) & 63, 64);
        float term = px * yn - py * xn;
#pragma unroll
        for (int off = 1; off < 64; off <<= 1) term += __shfl_xor(term, off, 64);
        float inter = 0.5f * fabsf(term);

        float uni = areaA + areaB - inter;
        float iou = inter / fmaxf(uni, 1e-12f);

        if (lane == 0) {
            float mf = (float)mask[row];
            float alpha = -logf(fabsf(iou) + EPS_F);
            float li = alpha * sl1 / (fabsf(sl1) + EPS_F);
            rowSl1[row] = sl1 * mf;
            rowLi[row]  = li * mf;
        }
    }
}

__global__ __launch_bounds__(256) void iou_reduce_kernel(
    const float* __restrict__ rowSl1, const float* __restrict__ rowLi,
    const int* __restrict__ mask, float* __restrict__ out)
{
    __shared__ float s1[256], s2[256], s3[256];
    const int tid = threadIdx.x;
    float a = 0.f, c = 0.f, msum = 0.f;
    for (int i = tid; i < 1024; i += 256) {
        a += rowSl1[i];
        c += rowLi[i];
        msum += (float)mask[i];
    }
    s1[tid] = a; s2[tid] = c; s3[tid] = msum;
    __syncthreads();
    for (int off = 128; off > 0; off >>= 1) {
        if (tid < off) {
            s1[tid] += s1[tid + off];
            s2[tid] += s2[tid + off];
            s3[tid] += s3[tid + off];
        }
        __syncthreads();
    }
    if (tid == 0) {
        float cnt = fmaxf(s3[0], 1.0f);
        out[0] = s1[0] / cnt;
        out[1] = s2[0] / cnt;
    }
}

extern "C" void kernel_launch(void* const* d_in, const int* in_sizes, int n_in,
                              void* d_out, int out_size, void* d_ws, size_t ws_size,
                              hipStream_t stream) {
    const float* output = (const float*)d_in[0];
    const int*   mask   = (const int*)d_in[1];
    const int*   ind    = (const int*)d_in[2];
    const float* target = (const float*)d_in[3];
    float* out    = (float*)d_out;
    float* rowSl1 = (float*)d_ws;
    float* rowLi  = rowSl1 + 1024;

    iou_row_kernel<<<1024, 256, 0, stream>>>(output, mask, ind, target, rowSl1, rowLi);
    iou_reduce_kernel<<<1, 256, 0, stream>>>(rowSl1, rowLi, mask, out);
}

// Round 6
// 21.434 us; speedup vs baseline: 3.2772x; 1.0273x over previous
//
#include <hip/hip_runtime.h>
#include <math.h>

#define NPAIR 630
#define EPS_F 1.1920928955078125e-07f   // np.finfo(float32).eps

__device__ __forceinline__ float rl(float v, int l) {   // uniform lane read -> SGPR
    return __int_as_float(__builtin_amdgcn_readlane(__float_as_int(v), l));
}

// decode pair index m in [0,630) -> (i,j), i<j<36, row-major triu order
__device__ __forceinline__ void decode_pair(int m, int& pi, int& pj) {
    int i = (int)((71.0f - sqrtf(5041.0f - 8.0f * (float)m)) * 0.5f);
    i = max(0, min(34, i));
    while (i > 0 && m < i * (71 - i) / 2) --i;
    while (i < 34 && m >= (i + 1) * (70 - i) / 2) ++i;
    pi = i;
    pj = m - i * (71 - i) / 2 + i + 1;
}

// pts[i] for i in [0,36): lanes 0-17 hold base coords; i>=18 is exact negation
__device__ __forceinline__ float fetch_pt(float v, int i) {
    int ii = (i < 18) ? i : (i - 18);
    float r = __shfl(v, ii, 64);
    return (i < 18) ? r : -r;
}

__device__ __forceinline__ float shoe4(float X0,float Y0,float X1,float Y1,
                                       float X2,float Y2,float X3,float Y3) {
    float s = 0.f;
    s += X0 * Y1 - Y0 * X1;
    s += X1 * Y2 - Y1 * X2;
    s += X2 * Y3 - Y2 * X3;
    s += X3 * Y0 - Y3 * X0;
    return 0.5f * fabsf(s);
}

// scan pairs m = lane + 64*sub + 128*it (it<5); packed (area,m) min
__device__ __forceinline__ unsigned long long pair_scan(
    const float* PX, const float* PY, float xv, float yv, int lane, int sub)
{
    unsigned long long best = ~0ULL;
#pragma unroll
    for (int it = 0; it < 5; ++it) {
        int m = lane + (sub << 6) + (it << 7);
        if (m < NPAIR) {
            int i, j; decode_pair(m, i, j);
            float xi = fetch_pt(xv, i), yi = fetch_pt(yv, i);
            float xj = fetch_pt(xv, j), yj = fetch_pt(yv, j);
            float dx = xj - xi, dy = yj - yi;
            float nrm = sqrtf(dx * dx + dy * dy);
            float inv = 1.f / fmaxf(nrm, 1e-9f);
            float ux = dx * inv, uy = dy * inv;
            float vx = -uy, vy = ux;
            float umax = 0.f, vmax = 0.f;   // max |proj| == fmax(pmax,-pmin) exactly
#pragma unroll
            for (int kk = 0; kk < 18; ++kk) {
                float x = PX[kk], y = PY[kk];
                float pu = ux * x + uy * y;
                float pv = vx * x + vy * y;
                umax = fmaxf(umax, fabsf(pu));
                vmax = fmaxf(vmax, fabsf(pv));
            }
            float area = (umax + umax) * (vmax + vmax);
            area = (nrm > 1e-9f) ? area : INFINITY;
            unsigned long long key =
                ((unsigned long long)__float_as_uint(area) << 32) | (unsigned)m;
            if (key < best) best = key;
        }
    }
#pragma unroll
    for (int off = 1; off < 64; off <<= 1) {
        unsigned long long o = __shfl_xor(best, off, 64);
        if (o < best) best = o;
    }
    return best;
}

// finalize rect from winning pair key; corners in CCW construction order
// (== reference's angle-sorted cycle up to rotation; shoelace and
// Sutherland-Hodgman are cyclic-rotation-invariant)
__device__ __forceinline__ void rect_finalize(
    const float* PX, const float* PY, float xv, float yv,
    unsigned long long key,
    float& c0x, float& c0y, float& c1x, float& c1y,
    float& c2x, float& c2y, float& c3x, float& c3y)
{
    int m = (int)(key & 0xFFFFFFFFULL);
    int i, j; decode_pair(m, i, j);
    float xi = fetch_pt(xv, i), yi = fetch_pt(yv, i);
    float xj = fetch_pt(xv, j), yj = fetch_pt(yv, j);
    float dx = xj - xi, dy = yj - yi;
    float nrm = sqrtf(dx * dx + dy * dy);
    float inv = 1.f / fmaxf(nrm, 1e-9f);
    float ux = dx * inv, uy = dy * inv;
    float vx = -uy, vy = ux;
    float umax = 0.f, vmax = 0.f;
#pragma unroll
    for (int kk = 0; kk < 18; ++kk) {
        float x = PX[kk], y = PY[kk];
        float pu = ux * x + uy * y;
        float pv = vx * x + vy * y;
        umax = fmaxf(umax, fabsf(pu));
        vmax = fmaxf(vmax, fabsf(pv));
    }
    float umin = -umax, vmin = -vmax;
    c0x = umin * ux + vmin * vx;  c0y = umin * uy + vmin * vy;
    c1x = umax * ux + vmin * vx;  c1y = umax * uy + vmin * vy;
    c2x = umax * ux + vmax * vx;  c2y = umax * uy + vmax * vy;
    c3x = umin * ux + vmax * vx;  c3y = umin * uy + vmax * vy;
}

// one Sutherland-Hodgman step, literal lane-parallel copy of _clip_halfplane.
// Lanes >= 2K are don't-care at intermediate steps (next step reads only
// lanes < 2K), so the prefix-max is capped at 2K levels.
template <int K>
__device__ __forceinline__ void clip_step(float& x, float& y,
    float e1x, float e1y, float e2x, float e2y, int lane)
{
    const float dex = e2x - e1x, dey = e2y - e1y;
    float side = dex * (y - e1y) - dey * (x - e1x);
    int nl = (lane + 1) & (K - 1);
    float xn = __shfl(x, nl, 64);
    float yn = __shfl(y, nl, 64);
    float siden = __shfl(side, nl, 64);
    float denom = side - siden;
    float dd = (fabsf(denom) < 1e-12f) ? 1e-12f : denom;
    float t = side / dd;
    float ix = x + t * (xn - x);
    float iy = y + t * (yn - y);
    bool s_in = side >= 0.f, e_in = siden >= 0.f;
    int flags = (s_in ? 1 : 0) | (e_in ? 2 : 0);
    int src = lane >> 1;
    float ex  = __shfl(ix, src, 64);
    float ey  = __shfl(iy, src, 64);
    float nx2 = __shfl(xn, src, 64);
    float ny2 = __shfl(yn, src, 64);
    int   f2  = __shfl(flags, src, 64);
    bool odd = (lane & 1) != 0;
    float ox = odd ? nx2 : ex;
    float oy = odd ? ny2 : ey;
    bool sin2 = (f2 & 1) != 0, ein2 = (f2 & 2) != 0;
    bool vj = odd ? ein2 : (sin2 != ein2);
    vj = vj && (lane < 2 * K);
    int idx = vj ? lane : -1;
#pragma unroll
    for (int off = 1; off < 2 * K; off <<= 1) {
        int o = __shfl_up(idx, off, 64);
        if (lane >= off && o > idx) idx = o;
    }
    unsigned long long bal = __ballot(vj);
    int firstv = (int)__ffsll(bal) - 1;
    int gi = (idx >= 0) ? idx : firstv;
    float gx = __shfl(ox, gi, 64);
    float gy = __shfl(oy, gi, 64);
    if (bal == 0ULL) { gx = 0.f; gy = 0.f; }
    x = gx; y = gy;
}

__global__ __launch_bounds__(256) void iou_row_kernel(
    const float* __restrict__ output, const int* __restrict__ mask,
    const int* __restrict__ ind, const float* __restrict__ target,
    float* __restrict__ rowSl1, float* __restrict__ rowLi)
{
    const int row  = blockIdx.x;      // 0 .. 1023
    const int b    = row >> 6;
    const int tid  = threadIdx.x;
    const int lane = tid & 63;
    const int wid  = tid >> 6;        // 0..3
    const int poly = wid >> 1;        // waves 0,1 -> pred; 2,3 -> target
    const int sub  = wid & 1;

    __shared__ unsigned long long wkey[4];
    __shared__ float cXs[4], cYs[4];  // poly-1 corners

    const int idx = ind[row];
    float p = 0.f, t = 0.f, termv = 0.f, cosv = 0.f, sinv = 0.f;
    if (lane < 18) {
        float ang = (float)lane * ((float)M_PI / 18.0f);
        cosv = cosf(ang); sinv = sinf(ang);
        if (poly == 0) p = output[(size_t)(b * 18 + lane) * 65536 + idx];
        if (poly == 1 || wid == 0) t = target[row * 18 + lane];
        if (wid == 0) {
            float d = p - t, ad = fabsf(d);
            termv = (ad < 1.f) ? 0.5f * d * d : (ad - 0.5f);
        }
    }
    float base = (poly == 0) ? p : t;
    float xv = base * cosv, yv = base * sinv;

    // wave-uniform broadcast of the 18 base points via readlane (SGPR-resident)
    float PX[18], PY[18];
#pragma unroll
    for (int k = 0; k < 18; ++k) {
        PX[k] = rl(xv, k);
        PY[k] = rl(yv, k);
    }

    unsigned long long best = pair_scan(PX, PY, xv, yv, lane, sub);
    if (lane == 0) wkey[wid] = best;

    // wave 0: smooth-L1 mean, sequential order (readlane chain, exact)
    float sl1 = 0.f;
    if (wid == 0) {
#pragma unroll
        for (int k = 0; k < 18; ++k) sl1 += rl(termv, k);
        sl1 = sl1 / 18.0f;
    }
    __syncthreads();

    float ax0,ay0,ax1,ay1,ax2,ay2,ax3,ay3;
    if (sub == 0) {   // wave 0 finalizes poly 0, wave 2 finalizes poly 1
        unsigned long long k0 = wkey[2 * poly], k1 = wkey[2 * poly + 1];
        unsigned long long kk = (k1 < k0) ? k1 : k0;
        rect_finalize(PX, PY, xv, yv, kk, ax0,ay0,ax1,ay1,ax2,ay2,ax3,ay3);
        if (wid == 2 && lane == 0) {
            cXs[0] = ax0; cYs[0] = ay0; cXs[1] = ax1; cYs[1] = ay1;
            cXs[2] = ax2; cYs[2] = ay2; cXs[3] = ax3; cYs[3] = ay3;
        }
    }
    __syncthreads();

    if (wid == 0) {
        float bx0 = cXs[0], by0 = cYs[0], bx1 = cXs[1], by1 = cYs[1];
        float bx2 = cXs[2], by2 = cYs[2], bx3 = cXs[3], by3 = cYs[3];

        float areaA = shoe4(ax0,ay0,ax1,ay1,ax2,ay2,ax3,ay3);
        float areaB = shoe4(bx0,by0,bx1,by1,bx2,by2,bx3,by3);

        int s3 = lane & 3;
        float px = (s3 == 0) ? ax0 : (s3 == 1) ? ax1 : (s3 == 2) ? ax2 : ax3;
        float py = (s3 == 0) ? ay0 : (s3 == 1) ? ay1 : (s3 == 2) ? ay2 : ay3;
        clip_step<4 >(px, py, bx0, by0, bx1, by1, lane);
        clip_step<8 >(px, py, bx1, by1, bx2, by2, lane);
        clip_step<16>(px, py, bx2, by2, bx3, by3, lane);
        clip_step<32>(px, py, bx3, by3, bx0, by0, lane);

        float xn = __shfl(px, (lane + 1) & 63, 64);
        float yn = __shfl(py, (lane + 1) & 63, 64);
        float term = px * yn - py * xn;
#pragma unroll
        for (int off = 1; off < 64; off <<= 1) term += __shfl_xor(term, off, 64);
        float inter = 0.5f * fabsf(term);

        float uni = areaA + areaB - inter;
        float iou = inter / fmaxf(uni, 1e-12f);

        if (lane == 0) {
            float mf = (float)mask[row];
            float alpha = -logf(fabsf(iou) + EPS_F);
            float li = alpha * sl1 / (fabsf(sl1) + EPS_F);
            rowSl1[row] = sl1 * mf;
            rowLi[row]  = li * mf;
        }
    }
}

__global__ __launch_bounds__(256) void iou_reduce_kernel(
    const float* __restrict__ rowSl1, const float* __restrict__ rowLi,
    const int* __restrict__ mask, float* __restrict__ out)
{
    __shared__ float s1[256], s2[256], s3[256];
    const int tid = threadIdx.x;
    float a = 0.f, c = 0.f, msum = 0.f;
    for (int i = tid; i < 1024; i += 256) {
        a += rowSl1[i];
        c += rowLi[i];
        msum += (float)mask[i];
    }
    s1[tid] = a; s2[tid] = c; s3[tid] = msum;
    __syncthreads();
    for (int off = 128; off > 0; off >>= 1) {
        if (tid < off) {
            s1[tid] += s1[tid + off];
            s2[tid] += s2[tid + off];
            s3[tid] += s3[tid + off];
        }
        __syncthreads();
    }
    if (tid == 0) {
        float cnt = fmaxf(s3[0], 1.0f);
        out[0] = s1[0] / cnt;
        out[1] = s2[0] / cnt;
    }
}

extern "C" void kernel_launch(void* const* d_in, const int* in_sizes, int n_in,
                              void* d_out, int out_size, void* d_ws, size_t ws_size,
                              hipStream_t stream) {
    const float* output = (const float*)d_in[0];
    const int*   mask   = (const int*)d_in[1];
    const int*   ind    = (const int*)d_in[2];
    const float* target = (const float*)d_in[3];
    float* out    = (float*)d_out;
    float* rowSl1 = (float*)d_ws;
    float* rowLi  = rowSl1 + 1024;

    iou_row_kernel<<<1024, 256, 0, stream>>>(output, mask, ind, target, rowSl1, rowLi);
    iou_reduce_kernel<<<1, 256, 0, stream>>>(rowSl1, rowLi, mask, out);
}

// Round 7
// 17.998 us; speedup vs baseline: 3.9028x; 1.1909x over previous
//
#include <hip/hip_runtime.h>
#include <math.h>

#define EPS_F 1.1920928955078125e-07f   // np.finfo(float32).eps

__device__ __forceinline__ float rl(float v, int l) {   // uniform lane read -> SGPR
    return __int_as_float(__builtin_amdgcn_readlane(__float_as_int(v), l));
}

// grid index q in [0,324) -> (a,b) in [0,18)^2  (magic-mul divide by 18)
__device__ __forceinline__ void decode_q(int q, int& a, int& b) {
    a = (q * 456) >> 13;        // == q/18 for 0 <= q < 324
    b = q - a * 18;
}

// Reconstruct the reference pair difference for grid point (a,b):
//   a<b : inner pair (a,b),       d = pts[b] - pts[a]
//   a>=b: cross pair (b, 18+a),   d = -pts[a] - pts[b]   (bit-exact rep)
// Also returns the ORIGINAL reference pair index m for tie-breaks.
__device__ __forceinline__ void pair_from_q(
    float xv, float yv, int q,
    float& dx, float& dy, int& m)
{
    int a, b; decode_q(q, a, b);
    float xA = __shfl(xv, a, 64), yA = __shfl(yv, a, 64);
    float xB = __shfl(xv, b, 64), yB = __shfl(yv, b, 64);
    bool inner = a < b;
    dx = inner ? (xB - xA) : (-(xA + xB));
    dy = inner ? (yB - yA) : (-(yA + yB));
    int i1 = inner ? a : b;
    int j1 = inner ? b : (a + 18);
    m = (i1 * (71 - i1)) / 2 + j1 - i1 - 1;
}

__device__ __forceinline__ float shoe4(float X0,float Y0,float X1,float Y1,
                                       float X2,float Y2,float X3,float Y3) {
    float s = 0.f;
    s += X0 * Y1 - Y0 * X1;
    s += X1 * Y2 - Y1 * X2;
    s += X2 * Y3 - Y2 * X3;
    s += X3 * Y0 - Y3 * X0;
    return 0.5f * fabsf(s);
}

// scan grid pairs q = lane + 64*sw + 256*it (it<2); packed (area, m, q) min
__device__ __forceinline__ unsigned long long pair_scan(
    const float* PX, const float* PY, float xv, float yv, int lane, int sw)
{
    unsigned long long best = ~0ULL;
#pragma unroll
    for (int it = 0; it < 2; ++it) {
        int q = lane + (sw << 6) + (it << 8);
        if (q < 324) {
            float dx, dy; int m;
            pair_from_q(xv, yv, q, dx, dy, m);
            float nrm = sqrtf(dx * dx + dy * dy);
            float inv = 1.f / fmaxf(nrm, 1e-9f);
            float ux = dx * inv, uy = dy * inv;
            float vx = -uy, vy = ux;
            float umax = 0.f, vmax = 0.f;   // max |proj| == fmax(pmax,-pmin) exactly
#pragma unroll
            for (int kk = 0; kk < 18; ++kk) {
                float x = PX[kk], y = PY[kk];
                float pu = ux * x + uy * y;
                float pv = vx * x + vy * y;
                umax = fmaxf(umax, fabsf(pu));
                vmax = fmaxf(vmax, fabsf(pv));
            }
            float area = (umax + umax) * (vmax + vmax);
            area = (nrm > 1e-9f) ? area : INFINITY;
            unsigned long long key =
                ((unsigned long long)__float_as_uint(area) << 32)
                | ((unsigned)m << 16) | (unsigned)q;
            if (key < best) best = key;
        }
    }
#pragma unroll
    for (int off = 1; off < 64; off <<= 1) {
        unsigned long long o = __shfl_xor(best, off, 64);
        if (o < best) best = o;
    }
    return best;
}

// finalize rect from winning key (low 16 bits = grid q); corners in CCW
// construction order (== reference's angle-sorted cycle up to rotation;
// shoelace and Sutherland-Hodgman are cyclic-rotation-invariant)
__device__ __forceinline__ void rect_finalize(
    const float* PX, const float* PY, float xv, float yv,
    unsigned long long key,
    float& c0x, float& c0y, float& c1x, float& c1y,
    float& c2x, float& c2y, float& c3x, float& c3y)
{
    int q = (int)(key & 0xFFFFULL);
    float dx, dy; int m_unused;
    pair_from_q(xv, yv, q, dx, dy, m_unused);
    float nrm = sqrtf(dx * dx + dy * dy);
    float inv = 1.f / fmaxf(nrm, 1e-9f);
    float ux = dx * inv, uy = dy * inv;
    float vx = -uy, vy = ux;
    float umax = 0.f, vmax = 0.f;
#pragma unroll
    for (int kk = 0; kk < 18; ++kk) {
        float x = PX[kk], y = PY[kk];
        float pu = ux * x + uy * y;
        float pv = vx * x + vy * y;
        umax = fmaxf(umax, fabsf(pu));
        vmax = fmaxf(vmax, fabsf(pv));
    }
    float umin = -umax, vmin = -vmax;
    c0x = umin * ux + vmin * vx;  c0y = umin * uy + vmin * vy;
    c1x = umax * ux + vmin * vx;  c1y = umax * uy + vmin * vy;
    c2x = umax * ux + vmax * vx;  c2y = umax * uy + vmax * vy;
    c3x = umin * ux + vmax * vx;  c3y = umin * uy + vmax * vy;
}

// one Sutherland-Hodgman step, literal lane-parallel copy of _clip_halfplane.
// Lanes >= 2K are don't-care at intermediate steps, so prefix-max capped at 2K.
template <int K>
__device__ __forceinline__ void clip_step(float& x, float& y,
    float e1x, float e1y, float e2x, float e2y, int lane)
{
    const float dex = e2x - e1x, dey = e2y - e1y;
    float side = dex * (y - e1y) - dey * (x - e1x);
    int nl = (lane + 1) & (K - 1);
    float xn = __shfl(x, nl, 64);
    float yn = __shfl(y, nl, 64);
    float siden = __shfl(side, nl, 64);
    float denom = side - siden;
    float dd = (fabsf(denom) < 1e-12f) ? 1e-12f : denom;
    float t = side / dd;
    float ix = x + t * (xn - x);
    float iy = y + t * (yn - y);
    bool s_in = side >= 0.f, e_in = siden >= 0.f;
    int flags = (s_in ? 1 : 0) | (e_in ? 2 : 0);
    int src = lane >> 1;
    float ex  = __shfl(ix, src, 64);
    float ey  = __shfl(iy, src, 64);
    float nx2 = __shfl(xn, src, 64);
    float ny2 = __shfl(yn, src, 64);
    int   f2  = __shfl(flags, src, 64);
    bool odd = (lane & 1) != 0;
    float ox = odd ? nx2 : ex;
    float oy = odd ? ny2 : ey;
    bool sin2 = (f2 & 1) != 0, ein2 = (f2 & 2) != 0;
    bool vj = odd ? ein2 : (sin2 != ein2);
    vj = vj && (lane < 2 * K);
    int idx = vj ? lane : -1;
#pragma unroll
    for (int off = 1; off < 2 * K; off <<= 1) {
        int o = __shfl_up(idx, off, 64);
        if (lane >= off && o > idx) idx = o;
    }
    unsigned long long bal = __ballot(vj);
    int firstv = (int)__ffsll(bal) - 1;
    int gi = (idx >= 0) ? idx : firstv;
    float gx = __shfl(ox, gi, 64);
    float gy = __shfl(oy, gi, 64);
    if (bal == 0ULL) { gx = 0.f; gy = 0.f; }
    x = gx; y = gy;
}

__global__ __launch_bounds__(512) void iou_row_kernel(
    const float* __restrict__ output, const int* __restrict__ mask,
    const int* __restrict__ ind, const float* __restrict__ target,
    float* __restrict__ rowSl1, float* __restrict__ rowLi)
{
    const int row  = blockIdx.x;      // 0 .. 1023
    const int b    = row >> 6;
    const int tid  = threadIdx.x;
    const int lane = tid & 63;
    const int wid  = tid >> 6;        // 0..7
    const int poly = wid >> 2;        // waves 0-3 -> pred; 4-7 -> target
    const int sw   = wid & 3;

    __shared__ unsigned long long wkey[8];
    __shared__ float cXs[4], cYs[4];  // poly-1 corners
    __shared__ float s_sl1;

    const int idx = ind[row];
    float p = 0.f, t = 0.f, termv = 0.f, cosv = 0.f, sinv = 0.f;
    if (lane < 18) {
        float ang = (float)lane * ((float)M_PI / 18.0f);
        cosv = cosf(ang); sinv = sinf(ang);
        if (poly == 0) p = output[(size_t)(b * 18 + lane) * 65536 + idx];
        if (poly == 1 || wid == 0) t = target[row * 18 + lane];
        if (wid == 0) {
            float d = p - t, ad = fabsf(d);
            termv = (ad < 1.f) ? 0.5f * d * d : (ad - 0.5f);
        }
    }
    float base = (poly == 0) ? p : t;
    float xv = base * cosv, yv = base * sinv;

    // wave-uniform broadcast of the 18 base points via readlane (SGPR-resident)
    float PX[18], PY[18];
#pragma unroll
    for (int k = 0; k < 18; ++k) {
        PX[k] = rl(xv, k);
        PY[k] = rl(yv, k);
    }

    unsigned long long best = pair_scan(PX, PY, xv, yv, lane, sw);
    if (lane == 0) wkey[wid] = best;

    // wave 0: smooth-L1 mean, sequential order (readlane chain, exact)
    if (wid == 0) {
        float sl1 = 0.f;
#pragma unroll
        for (int k = 0; k < 18; ++k) sl1 += rl(termv, k);
        if (lane == 0) s_sl1 = sl1 / 18.0f;
    }
    __syncthreads();

    float ax0,ay0,ax1,ay1,ax2,ay2,ax3,ay3;
    if (sw == 0) {   // wave 0 finalizes poly 0, wave 4 finalizes poly 1
        unsigned long long k0 = wkey[4 * poly + 0], k1 = wkey[4 * poly + 1];
        unsigned long long k2 = wkey[4 * poly + 2], k3 = wkey[4 * poly + 3];
        unsigned long long ka = (k1 < k0) ? k1 : k0;
        unsigned long long kb = (k3 < k2) ? k3 : k2;
        unsigned long long kk = (kb < ka) ? kb : ka;
        rect_finalize(PX, PY, xv, yv, kk, ax0,ay0,ax1,ay1,ax2,ay2,ax3,ay3);
        if (wid == 4 && lane == 0) {
            cXs[0] = ax0; cYs[0] = ay0; cXs[1] = ax1; cYs[1] = ay1;
            cXs[2] = ax2; cYs[2] = ay2; cXs[3] = ax3; cYs[3] = ay3;
        }
    }
    __syncthreads();

    if (wid == 0) {
        float bx0 = cXs[0], by0 = cYs[0], bx1 = cXs[1], by1 = cYs[1];
        float bx2 = cXs[2], by2 = cYs[2], bx3 = cXs[3], by3 = cYs[3];

        float areaA = shoe4(ax0,ay0,ax1,ay1,ax2,ay2,ax3,ay3);
        float areaB = shoe4(bx0,by0,bx1,by1,bx2,by2,bx3,by3);

        int s3 = lane & 3;
        float px = (s3 == 0) ? ax0 : (s3 == 1) ? ax1 : (s3 == 2) ? ax2 : ax3;
        float py = (s3 == 0) ? ay0 : (s3 == 1) ? ay1 : (s3 == 2) ? ay2 : ay3;
        clip_step<4 >(px, py, bx0, by0, bx1, by1, lane);
        clip_step<8 >(px, py, bx1, by1, bx2, by2, lane);
        clip_step<16>(px, py, bx2, by2, bx3, by3, lane);
        clip_step<32>(px, py, bx3, by3, bx0, by0, lane);

        float xn = __shfl(px, (lane + 1) & 63, 64);
        float yn = __shfl(py, (lane + 1) & 63, 64);
        float term = px * yn - py * xn;
#pragma unroll
        for (int off = 1; off < 64; off <<= 1) term += __shfl_xor(term, off, 64);
        float inter = 0.5f * fabsf(term);

        float uni = areaA + areaB - inter;
        float iou = inter / fmaxf(uni, 1e-12f);

        if (lane == 0) {
            float sl1 = s_sl1;
            float mf = (float)mask[row];
            float alpha = -logf(fabsf(iou) + EPS_F);
            float li = alpha * sl1 / (fabsf(sl1) + EPS_F);
            rowSl1[row] = sl1 * mf;
            rowLi[row]  = li * mf;
        }
    }
}

__global__ __launch_bounds__(256) void iou_reduce_kernel(
    const float* __restrict__ rowSl1, const float* __restrict__ rowLi,
    const int* __restrict__ mask, float* __restrict__ out)
{
    __shared__ float s1[256], s2[256], s3[256];
    const int tid = threadIdx.x;
    float a = 0.f, c = 0.f, msum = 0.f;
    for (int i = tid; i < 1024; i += 256) {
        a += rowSl1[i];
        c += rowLi[i];
        msum += (float)mask[i];
    }
    s1[tid] = a; s2[tid] = c; s3[tid] = msum;
    __syncthreads();
    for (int off = 128; off > 0; off >>= 1) {
        if (tid < off) {
            s1[tid] += s1[tid + off];
            s2[tid] += s2[tid + off];
            s3[tid] += s3[tid + off];
        }
        __syncthreads();
    }
    if (tid == 0) {
        float cnt = fmaxf(s3[0], 1.0f);
        out[0] = s1[0] / cnt;
        out[1] = s2[0] / cnt;
    }
}

extern "C" void kernel_launch(void* const* d_in, const int* in_sizes, int n_in,
                              void* d_out, int out_size, void* d_ws, size_t ws_size,
                              hipStream_t stream) {
    const float* output = (const float*)d_in[0];
    const int*   mask   = (const int*)d_in[1];
    const int*   ind    = (const int*)d_in[2];
    const float* target = (const float*)d_in[3];
    float* out    = (float*)d_out;
    float* rowSl1 = (float*)d_ws;
    float* rowLi  = rowSl1 + 1024;

    iou_row_kernel<<<1024, 512, 0, stream>>>(output, mask, ind, target, rowSl1, rowLi);
    iou_reduce_kernel<<<1, 256, 0, stream>>>(rowSl1, rowLi, mask, out);
}

// Round 8
// 17.410 us; speedup vs baseline: 4.0347x; 1.0338x over previous
//
#include <hip/hip_runtime.h>
#include <math.h>

#define EPS_F 1.1920928955078125e-07f   // np.finfo(float32).eps

__device__ __forceinline__ float rl(float v, int l) {   // uniform lane read -> SGPR
    return __int_as_float(__builtin_amdgcn_readlane(__float_as_int(v), l));
}

// ---- DPP helpers (VALU-latency cross-lane, exact integer semantics) ----
// u64 min with row_ror<N> neighbor (all lanes valid for ror)
template <int CTRL>
__device__ __forceinline__ unsigned long long dpp_min_u64(unsigned long long best) {
    int lo = (int)(best & 0xFFFFFFFFULL), hi = (int)(best >> 32);
    int lo2 = __builtin_amdgcn_update_dpp(lo, lo, CTRL, 0xF, 0xF, false);
    int hi2 = __builtin_amdgcn_update_dpp(hi, hi, CTRL, 0xF, 0xF, false);
    unsigned long long o = ((unsigned long long)(unsigned)hi2 << 32) | (unsigned)lo2;
    return (o < best) ? o : best;
}
// i32 max scan step; lanes with no source (or masked rows) get identity -1
template <int CTRL, int RMASK>
__device__ __forceinline__ int dpp_max_i32(int v) {
    int o = __builtin_amdgcn_update_dpp(-1, v, CTRL, RMASK, 0xF, false);
    return (o > v) ? o : v;
}

// grid index q in [0,324) -> (a,b) in [0,18)^2  (magic-mul divide by 18)
__device__ __forceinline__ void decode_q(int q, int& a, int& b) {
    a = (q * 456) >> 13;        // == q/18 for 0 <= q < 324
    b = q - a * 18;
}

// Reconstruct the reference pair difference for grid point (a,b):
//   a<b : inner pair (a,b),       d = pts[b] - pts[a]
//   a>=b: cross pair (b, 18+a),   d = -pts[a] - pts[b]   (bit-exact rep)
// Also returns the ORIGINAL reference pair index m for tie-breaks.
__device__ __forceinline__ void pair_from_q(
    float xv, float yv, int q,
    float& dx, float& dy, int& m)
{
    int a, b; decode_q(q, a, b);
    float xA = __shfl(xv, a, 64), yA = __shfl(yv, a, 64);
    float xB = __shfl(xv, b, 64), yB = __shfl(yv, b, 64);
    bool inner = a < b;
    dx = inner ? (xB - xA) : (-(xA + xB));
    dy = inner ? (yB - yA) : (-(yA + yB));
    int i1 = inner ? a : b;
    int j1 = inner ? b : (a + 18);
    m = (i1 * (71 - i1)) / 2 + j1 - i1 - 1;
}

__device__ __forceinline__ float shoe4(float X0,float Y0,float X1,float Y1,
                                       float X2,float Y2,float X3,float Y3) {
    float s = 0.f;
    s += X0 * Y1 - Y0 * X1;
    s += X1 * Y2 - Y1 * X2;
    s += X2 * Y3 - Y2 * X3;
    s += X3 * Y0 - Y3 * X0;
    return 0.5f * fabsf(s);
}

// scan grid pairs q = lane + 64*sw + 256*it (it<2); packed (area, m, q) min
__device__ __forceinline__ unsigned long long pair_scan(
    const float* PX, const float* PY, float xv, float yv, int lane, int sw)
{
    unsigned long long best = ~0ULL;
#pragma unroll
    for (int it = 0; it < 2; ++it) {
        int q = lane + (sw << 6) + (it << 8);
        if (q < 324) {
            float dx, dy; int m;
            pair_from_q(xv, yv, q, dx, dy, m);
            float nrm = sqrtf(dx * dx + dy * dy);
            float inv = 1.f / fmaxf(nrm, 1e-9f);
            float ux = dx * inv, uy = dy * inv;
            float vx = -uy, vy = ux;
            float umax = 0.f, vmax = 0.f;   // max |proj| == fmax(pmax,-pmin) exactly
#pragma unroll
            for (int kk = 0; kk < 18; ++kk) {
                float x = PX[kk], y = PY[kk];
                float pu = ux * x + uy * y;
                float pv = vx * x + vy * y;
                umax = fmaxf(umax, fabsf(pu));
                vmax = fmaxf(vmax, fabsf(pv));
            }
            float area = (umax + umax) * (vmax + vmax);
            area = (nrm > 1e-9f) ? area : INFINITY;
            unsigned long long key =
                ((unsigned long long)__float_as_uint(area) << 32)
                | ((unsigned)m << 16) | (unsigned)q;
            if (key < best) best = key;
        }
    }
    // in-row rotate-reduce (integer min: order-invariant, exact)
    best = dpp_min_u64<0x121>(best);   // row_ror:1
    best = dpp_min_u64<0x122>(best);   // row_ror:2
    best = dpp_min_u64<0x124>(best);   // row_ror:4
    best = dpp_min_u64<0x128>(best);   // row_ror:8
    // cross-row combine
    {
        unsigned long long o = __shfl_xor(best, 16, 64);
        if (o < best) best = o;
        o = __shfl_xor(best, 32, 64);
        if (o < best) best = o;
    }
    return best;
}

// finalize rect from winning key (low 16 bits = grid q); corners in CCW
// construction order (== reference's angle-sorted cycle up to rotation;
// shoelace and Sutherland-Hodgman are cyclic-rotation-invariant)
__device__ __forceinline__ void rect_finalize(
    const float* PX, const float* PY, float xv, float yv,
    unsigned long long key,
    float& c0x, float& c0y, float& c1x, float& c1y,
    float& c2x, float& c2y, float& c3x, float& c3y)
{
    int q = (int)(key & 0xFFFFULL);
    float dx, dy; int m_unused;
    pair_from_q(xv, yv, q, dx, dy, m_unused);
    float nrm = sqrtf(dx * dx + dy * dy);
    float inv = 1.f / fmaxf(nrm, 1e-9f);
    float ux = dx * inv, uy = dy * inv;
    float vx = -uy, vy = ux;
    float umax = 0.f, vmax = 0.f;
#pragma unroll
    for (int kk = 0; kk < 18; ++kk) {
        float x = PX[kk], y = PY[kk];
        float pu = ux * x + uy * y;
        float pv = vx * x + vy * y;
        umax = fmaxf(umax, fabsf(pu));
        vmax = fmaxf(vmax, fabsf(pv));
    }
    float umin = -umax, vmin = -vmax;
    c0x = umin * ux + vmin * vx;  c0y = umin * uy + vmin * vy;
    c1x = umax * ux + vmin * vx;  c1y = umax * uy + vmin * vy;
    c2x = umax * ux + vmax * vx;  c2y = umax * uy + vmax * vy;
    c3x = umin * ux + vmax * vx;  c3y = umin * uy + vmax * vy;
}

// one Sutherland-Hodgman step, literal lane-parallel copy of _clip_halfplane.
// Lanes >= 2K are don't-care at intermediate steps. Prefix-max via DPP
// inclusive scan (integer max, exact match of the shfl_up version).
template <int K>
__device__ __forceinline__ void clip_step(float& x, float& y,
    float e1x, float e1y, float e2x, float e2y, int lane)
{
    const float dex = e2x - e1x, dey = e2y - e1y;
    float side = dex * (y - e1y) - dey * (x - e1x);
    int nl = (lane + 1) & (K - 1);
    float xn = __shfl(x, nl, 64);
    float yn = __shfl(y, nl, 64);
    float siden = __shfl(side, nl, 64);
    float denom = side - siden;
    float dd = (fabsf(denom) < 1e-12f) ? 1e-12f : denom;
    float t = side / dd;
    float ix = x + t * (xn - x);
    float iy = y + t * (yn - y);
    bool s_in = side >= 0.f, e_in = siden >= 0.f;
    int flags = (s_in ? 1 : 0) | (e_in ? 2 : 0);
    int src = lane >> 1;
    float ex  = __shfl(ix, src, 64);
    float ey  = __shfl(iy, src, 64);
    float nx2 = __shfl(xn, src, 64);
    float ny2 = __shfl(yn, src, 64);
    int   f2  = __shfl(flags, src, 64);
    bool odd = (lane & 1) != 0;
    float ox = odd ? nx2 : ex;
    float oy = odd ? ny2 : ey;
    bool sin2 = (f2 & 1) != 0, ein2 = (f2 & 2) != 0;
    bool vj = odd ? ein2 : (sin2 != ein2);
    vj = vj && (lane < 2 * K);
    // inclusive prefix-max of (valid ? lane : -1), correct for lanes < 2K
    int idx = vj ? lane : -1;
    idx = dpp_max_i32<0x111, 0xF>(idx);                  // row_shr:1
    idx = dpp_max_i32<0x112, 0xF>(idx);                  // row_shr:2
    idx = dpp_max_i32<0x114, 0xF>(idx);                  // row_shr:4
    if constexpr (2 * K > 8)  idx = dpp_max_i32<0x118, 0xF>(idx);  // row_shr:8
    if constexpr (2 * K > 16) idx = dpp_max_i32<0x142, 0xA>(idx);  // bcast15 -> rows 1,3
    if constexpr (2 * K > 32) idx = dpp_max_i32<0x143, 0xC>(idx);  // bcast31 -> rows 2,3
    unsigned long long bal = __ballot(vj);
    int firstv = (int)__ffsll(bal) - 1;
    int gi = (idx >= 0) ? idx : firstv;
    float gx = __shfl(ox, gi, 64);
    float gy = __shfl(oy, gi, 64);
    if (bal == 0ULL) { gx = 0.f; gy = 0.f; }
    x = gx; y = gy;
}

__global__ __launch_bounds__(512) void iou_row_kernel(
    const float* __restrict__ output, const int* __restrict__ mask,
    const int* __restrict__ ind, const float* __restrict__ target,
    float* __restrict__ rowSl1, float* __restrict__ rowLi)
{
    const int row  = blockIdx.x;      // 0 .. 1023
    const int b    = row >> 6;
    const int tid  = threadIdx.x;
    const int lane = tid & 63;
    const int wid  = tid >> 6;        // 0..7
    const int poly = wid >> 2;        // waves 0-3 -> pred; 4-7 -> target
    const int sw   = wid & 3;

    __shared__ unsigned long long wkey[8];
    __shared__ float cXs[4], cYs[4];  // poly-1 corners
    __shared__ float s_sl1;

    const int idx = ind[row];
    float p = 0.f, t = 0.f, termv = 0.f, cosv = 0.f, sinv = 0.f;
    if (lane < 18) {
        float ang = (float)lane * ((float)M_PI / 18.0f);
        cosv = cosf(ang); sinv = sinf(ang);
        if (poly == 0) p = output[(size_t)(b * 18 + lane) * 65536 + idx];
        if (poly == 1 || wid == 0) t = target[row * 18 + lane];
        if (wid == 0) {
            float d = p - t, ad = fabsf(d);
            termv = (ad < 1.f) ? 0.5f * d * d : (ad - 0.5f);
        }
    }
    float base = (poly == 0) ? p : t;
    float xv = base * cosv, yv = base * sinv;

    // wave-uniform broadcast of the 18 base points via readlane (SGPR-resident)
    float PX[18], PY[18];
#pragma unroll
    for (int k = 0; k < 18; ++k) {
        PX[k] = rl(xv, k);
        PY[k] = rl(yv, k);
    }

    unsigned long long best = pair_scan(PX, PY, xv, yv, lane, sw);
    if (lane == 0) wkey[wid] = best;

    // wave 0: smooth-L1 mean, sequential order (readlane chain, exact)
    if (wid == 0) {
        float sl1 = 0.f;
#pragma unroll
        for (int k = 0; k < 18; ++k) sl1 += rl(termv, k);
        if (lane == 0) s_sl1 = sl1 / 18.0f;
    }
    __syncthreads();

    float ax0,ay0,ax1,ay1,ax2,ay2,ax3,ay3;
    if (sw == 0) {   // wave 0 finalizes poly 0, wave 4 finalizes poly 1
        unsigned long long k0 = wkey[4 * poly + 0], k1 = wkey[4 * poly + 1];
        unsigned long long k2 = wkey[4 * poly + 2], k3 = wkey[4 * poly + 3];
        unsigned long long ka = (k1 < k0) ? k1 : k0;
        unsigned long long kb = (k3 < k2) ? k3 : k2;
        unsigned long long kk = (kb < ka) ? kb : ka;
        rect_finalize(PX, PY, xv, yv, kk, ax0,ay0,ax1,ay1,ax2,ay2,ax3,ay3);
        if (wid == 4 && lane == 0) {
            cXs[0] = ax0; cYs[0] = ay0; cXs[1] = ax1; cYs[1] = ay1;
            cXs[2] = ax2; cYs[2] = ay2; cXs[3] = ax3; cYs[3] = ay3;
        }
    }
    __syncthreads();

    if (wid == 0) {
        float bx0 = cXs[0], by0 = cYs[0], bx1 = cXs[1], by1 = cYs[1];
        float bx2 = cXs[2], by2 = cYs[2], bx3 = cXs[3], by3 = cYs[3];

        float areaA = shoe4(ax0,ay0,ax1,ay1,ax2,ay2,ax3,ay3);
        float areaB = shoe4(bx0,by0,bx1,by1,bx2,by2,bx3,by3);

        int s3 = lane & 3;
        float px = (s3 == 0) ? ax0 : (s3 == 1) ? ax1 : (s3 == 2) ? ax2 : ax3;
        float py = (s3 == 0) ? ay0 : (s3 == 1) ? ay1 : (s3 == 2) ? ay2 : ay3;
        clip_step<4 >(px, py, bx0, by0, bx1, by1, lane);
        clip_step<8 >(px, py, bx1, by1, bx2, by2, lane);
        clip_step<16>(px, py, bx2, by2, bx3, by3, lane);
        clip_step<32>(px, py, bx3, by3, bx0, by0, lane);

        float xn = __shfl(px, (lane + 1) & 63, 64);
        float yn = __shfl(py, (lane + 1) & 63, 64);
        float term = px * yn - py * xn;
#pragma unroll
        for (int off = 1; off < 64; off <<= 1) term += __shfl_xor(term, off, 64);
        float inter = 0.5f * fabsf(term);

        float uni = areaA + areaB - inter;
        float iou = inter / fmaxf(uni, 1e-12f);

        if (lane == 0) {
            float sl1 = s_sl1;
            float mf = (float)mask[row];
            float alpha = -logf(fabsf(iou) + EPS_F);
            float li = alpha * sl1 / (fabsf(sl1) + EPS_F);
            rowSl1[row] = sl1 * mf;
            rowLi[row]  = li * mf;
        }
    }
}

__global__ __launch_bounds__(256) void iou_reduce_kernel(
    const float* __restrict__ rowSl1, const float* __restrict__ rowLi,
    const int* __restrict__ mask, float* __restrict__ out)
{
    __shared__ float s1[256], s2[256], s3[256];
    const int tid = threadIdx.x;
    float a = 0.f, c = 0.f, msum = 0.f;
    for (int i = tid; i < 1024; i += 256) {
        a += rowSl1[i];
        c += rowLi[i];
        msum += (float)mask[i];
    }
    s1[tid] = a; s2[tid] = c; s3[tid] = msum;
    __syncthreads();
    for (int off = 128; off > 0; off >>= 1) {
        if (tid < off) {
            s1[tid] += s1[tid + off];
            s2[tid] += s2[tid + off];
            s3[tid] += s3[tid + off];
        }
        __syncthreads();
    }
    if (tid == 0) {
        float cnt = fmaxf(s3[0], 1.0f);
        out[0] = s1[0] / cnt;
        out[1] = s2[0] / cnt;
    }
}

extern "C" void kernel_launch(void* const* d_in, const int* in_sizes, int n_in,
                              void* d_out, int out_size, void* d_ws, size_t ws_size,
                              hipStream_t stream) {
    const float* output = (const float*)d_in[0];
    const int*   mask   = (const int*)d_in[1];
    const int*   ind    = (const int*)d_in[2];
    const float* target = (const float*)d_in[3];
    float* out    = (float*)d_out;
    float* rowSl1 = (float*)d_ws;
    float* rowLi  = rowSl1 + 1024;

    iou_row_kernel<<<1024, 512, 0, stream>>>(output, mask, ind, target, rowSl1, rowLi);
    iou_reduce_kernel<<<1, 256, 0, stream>>>(rowSl1, rowLi, mask, out);
}